// Round 9
// baseline (410.268 us; speedup 1.0000x reference)
//
#include <hip/hip_runtime.h>
#include <cstdint>
#include <cstddef>
#include <math.h>

typedef unsigned short u16;
typedef __attribute__((ext_vector_type(8))) short short8;
typedef __attribute__((ext_vector_type(4))) float floatx4;

#define HIDDEN 1024
#define NHEAD 16
#define HD 64
#define BB 4
#define TT 2048
#define MM (BB*TT)      /* 8192 rows of x */
#define NQKV 3072
#define NEGINF (-30000.0f)

__device__ inline u16 f2bf(float f){
  union { float f; unsigned u; } v; v.f = f;
  unsigned r = v.u + 0x7FFFu + ((v.u >> 16) & 1u);
  return (u16)(r >> 16);
}
__device__ inline void load_lds16(const void* g, void* l){
  __builtin_amdgcn_global_load_lds((const __attribute__((address_space(1))) void*)g,
                                   (__attribute__((address_space(3))) void*)l,
                                   16, 0, 0);
}
// 8 consecutive f32 -> bf16x8 via hardware v_cvt_pk_bf16_f32 (RNE), 4 ops
__device__ inline short8 cvt8(const float* p){
  const floatx4 a = *(const floatx4*)p;
  const floatx4 b = *(const floatx4*)(p + 4);
  union { short8 s; unsigned u[4]; } r;
  asm("v_cvt_pk_bf16_f32 %0, %1, %2" : "=v"(r.u[0]) : "v"(a[0]), "v"(a[1]));
  asm("v_cvt_pk_bf16_f32 %0, %1, %2" : "=v"(r.u[1]) : "v"(a[2]), "v"(a[3]));
  asm("v_cvt_pk_bf16_f32 %0, %1, %2" : "=v"(r.u[2]) : "v"(b[0]), "v"(b[1]));
  asm("v_cvt_pk_bf16_f32 %0, %1, %2" : "=v"(r.u[3]) : "v"(b[2]), "v"(b[3]));
  return r.s;
}

// ---------------- fused prep: convert_x + transpose(Wqkv) + transpose(Wproj) + rope + tail ----
#define PREP_CONV_BLKS  4096                 /* 8192*1024/(256*8) */
#define PREP_TQKV_BLKS  (96*32)              /* (3072/32)*(1024/32) */
#define PREP_TPROJ_BLKS (32*32)
#define PREP_ROPE_BLKS  (TT*32/256)          /* 256 */
#define PREP_TAIL_BLKS  ((BB*HIDDEN+255)/256)/* 16 */
#define PREP_BLKS (PREP_CONV_BLKS + PREP_TQKV_BLKS + PREP_TPROJ_BLKS + PREP_ROPE_BLKS + PREP_TAIL_BLKS)

__global__ void prep(const float* __restrict__ x, u16* __restrict__ xN,
                     const float* __restrict__ Wqkv, u16* __restrict__ WqkvT,
                     const float* __restrict__ Wproj, u16* __restrict__ WprojT,
                     float* __restrict__ ropeC, float* __restrict__ ropeS,
                     const float* __restrict__ rnn, float* __restrict__ out)
{
  __shared__ alignas(16) u16 tile[32][33];
  int blk = blockIdx.x;
  const int tid = threadIdx.x;

  if (blk < PREP_CONV_BLKS){                 // ---- convert_x ----
    const int i = (blk * 256 + tid) * 8;
    #pragma unroll
    for (int u = 0; u < 8; u++) xN[i + u] = f2bf(x[i + u]);
    return;
  }
  blk -= PREP_CONV_BLKS;
  if (blk < PREP_TQKV_BLKS + PREP_TPROJ_BLKS){   // ---- transposes ----
    const float* in; u16* outp; int R, C, c0, r0;
    if (blk < PREP_TQKV_BLKS){
      in = Wqkv; outp = WqkvT; R = HIDDEN; C = NQKV;
      c0 = (blk % 96) * 32; r0 = (blk / 96) * 32;
    } else {
      const int b2 = blk - PREP_TQKV_BLKS;
      in = Wproj; outp = WprojT; R = HIDDEN; C = HIDDEN;
      c0 = (b2 % 32) * 32; r0 = (b2 / 32) * 32;
    }
    const int tx = tid & 31, ty = tid >> 5;  // 32 x 8
    for (int i = ty; i < 32; i += 8)
      tile[i][tx] = f2bf(in[(size_t)(r0 + i) * C + c0 + tx]);
    __syncthreads();
    for (int i = ty; i < 32; i += 8) outp[(size_t)(c0 + i) * R + r0 + tx] = tile[tx][i];
    return;
  }
  blk -= PREP_TQKV_BLKS + PREP_TPROJ_BLKS;
  if (blk < PREP_ROPE_BLKS){                 // ---- rope tables ----
    const int idx = blk * 256 + tid;         // t*32 + f
    const int t = idx >> 5, f = idx & 31;
    const float inv = powf(10000.0f, -(float)f * (1.0f / 32.0f));
    const float ang = (float)t * inv;
    ropeC[idx] = cosf(ang);
    ropeS[idx] = sinf(ang);
    return;
  }
  blk -= PREP_ROPE_BLKS;
  {                                          // ---- rnn_state tail ----
    const int i = blk * 256 + tid;
    if (i < BB * HIDDEN) out[(size_t)MM * HIDDEN + i] = rnn[i];
  }
}

// ---------------- GEMM1: qkv = x @ Wqkv + b, fused RoPE + head transpose ----------------
// (round-4 winner, unchanged)
__global__ void gemm_qkv(const u16* __restrict__ X, const u16* __restrict__ WT,
                         const float* __restrict__ bias,
                         const float* __restrict__ ropeC, const float* __restrict__ ropeS,
                         u16* __restrict__ Qb, u16* __restrict__ Kb, u16* __restrict__ Vtg)
{
  __shared__ alignas(16) u16 As[128 * 32];
  __shared__ alignas(16) u16 Bs[128 * 32];
  __shared__ alignas(16) u16 VTx[4][64 * 24];   // per-wave V-transpose tile ([d][t16], pad 24)
  const int tid = threadIdx.x;
  const int wid = tid >> 6, lane = tid & 63;
  const int quad = lane >> 4, ln = lane & 15;
  const int row0 = blockIdx.y * 128, col0 = blockIdx.x * 128;
  const int wm = (wid >> 1) * 64, wn = (wid & 1) * 64;
  floatx4 acc[4][4] = {};

  const int sr = tid >> 2, sk = (tid & 3) * 8;

  for (int kk = 0; kk < 32; ++kk){
    const int k0 = kk * 32;
    __syncthreads();
    load_lds16(&X [(size_t)(row0 + sr      ) * 1024 + k0 + sk], &As[(size_t)(tid      ) * 8]);
    load_lds16(&X [(size_t)(row0 + sr + 64 ) * 1024 + k0 + sk], &As[(size_t)(tid + 256) * 8]);
    load_lds16(&WT[(size_t)(col0 + sr      ) * 1024 + k0 + sk], &Bs[(size_t)(tid      ) * 8]);
    load_lds16(&WT[(size_t)(col0 + sr + 64 ) * 1024 + k0 + sk], &Bs[(size_t)(tid + 256) * 8]);
    __syncthreads();
    short8 a[4], b[4];
    #pragma unroll
    for (int i = 0; i < 4; i++) a[i] = *(const short8*)&As[(wm + i*16 + ln) * 32 + quad * 8];
    #pragma unroll
    for (int j = 0; j < 4; j++) b[j] = *(const short8*)&Bs[(wn + j*16 + ln) * 32 + quad * 8];
    #pragma unroll
    for (int i = 0; i < 4; i++)
      #pragma unroll
      for (int j = 0; j < 4; j++)
        acc[i][j] = __builtin_amdgcn_mfma_f32_16x16x32_bf16(a[i], b[j], acc[i][j], 0, 0, 0);
  }

  // epilogue: C-layout col = lane&15, row = quad*4 + reg
  const int wcol0 = col0 + wn;            // 64-aligned -> single (which, head) per wave
  const int which = wcol0 >> 10;          // 0=q 1=k 2=v  (block-uniform: col0 is 128-aligned)
  const int h = (wcol0 & 1023) >> 6;
  float bs[4];
  #pragma unroll
  for (int j = 0; j < 4; j++) bs[j] = bias[wcol0 + j*16 + ln];

  if (which < 2){
    #pragma unroll
    for (int i = 0; i < 4; i++){
      #pragma unroll
      for (int rr = 0; rr < 4; rr++){
        const int rowg = row0 + wm + i*16 + quad*4 + rr;
        const int b_ = rowg >> 11, t = rowg & 2047;
        u16* op = (which == 0 ? Qb : Kb) + ((size_t)(b_ * NHEAD + h) * TT + t) * HD;
        #pragma unroll
        for (int j = 0; j < 2; j++){
          const int f = j*16 + ln;
          const float cs = ropeC[t * 32 + f];
          const float sn = ropeS[t * 32 + f];
          const float x1 = acc[i][j  ][rr] + bs[j  ];
          const float x2 = acc[i][j+2][rr] + bs[j+2];
          float y1 = x1 * cs - x2 * sn;
          float y2 = x1 * sn + x2 * cs;
          if (which == 0){ y1 *= 0.125f; y2 *= 0.125f; }
          op[f]      = f2bf(y1);
          op[f + 32] = f2bf(y2);
        }
      }
    }
  } else {
    // V: per-wave LDS transpose in 16-t chunks -> coalesced 16B stores along t.
    #pragma unroll
    for (int i = 0; i < 4; i++){
      #pragma unroll
      for (int j = 0; j < 4; j++)
        #pragma unroll
        for (int rr = 0; rr < 4; rr++)
          VTx[wid][(j*16 + ln) * 24 + quad*4 + rr] = f2bf(acc[i][j][rr] + bs[j]);
      asm volatile("s_waitcnt lgkmcnt(0)" ::: "memory");   // cross-lane in-wave LDS RAW
      const int d = lane;                                   // 0..63
      const short8 v0 = *(const short8*)&VTx[wid][d * 24 + 0];
      const short8 v1 = *(const short8*)&VTx[wid][d * 24 + 8];
      const int rowg = row0 + wm + i*16;
      const int b_ = rowg >> 11, t0 = rowg & 2047;
      u16* vp = &Vtg[((size_t)(b_ * NHEAD + h) * HD + d) * TT + t0];
      *(short8*)&vp[0] = v0;
      *(short8*)&vp[8] = v1;
      asm volatile("s_waitcnt lgkmcnt(0)" ::: "memory");   // reads done before next chunk's writes
    }
  }
}

// ---------------- flash attention v11: NO K/V staging, NO barriers ----------------
// Lesson #7 (measured): don't LDS-stage data the caches hold. Per-bh K/V = 512 KB,
// L2-resident; a block's 4 waves re-read the same chunk -> L1 hits. MFMA fragments
// load DIRECTLY from global: kb = K[key][d] rows (64B/row span), vb = V^T[d][t]
// (16B contiguous/lane). Zero __syncthreads: waves run free, each with its OWN
// exact chunk count ((qbase+31)>>6)+1 — no masked iterations, no lockstep stalls.
// LDS = Plf only (17408 B). Per-qt processing caps VGPR (~100) -> 4 waves/SIMD.
__global__ void __launch_bounds__(256, 4)
attn(const u16* __restrict__ Qb, const u16* __restrict__ Kb,
     const u16* __restrict__ Vtg, u16* __restrict__ AO)
{
  const int bh = blockIdx.x, tbi = 15 - (int)blockIdx.y;
  const int tid = threadIdx.x;
  const int wid = tid >> 6, lane = tid & 63;
  const int quad = lane >> 4, ln = lane & 15;

  __shared__ alignas(16) float Plf[4][16 * 68];     // per-wave f32 P tile, stride 68 (bank-balanced)

  const u16* Qh = Qb  + (size_t)bh * TT * HD;
  const u16* Kh = Kb  + (size_t)bh * TT * HD;
  const u16* Vh = Vtg + (size_t)bh * HD * TT;       // [d][t]
  const int b_ = bh >> 4, h = bh & 15;

  const int qbase = tbi * 128 + wid * 32;           // wave owns rows [qbase, qbase+31]

  short8 aq[2][2];
  #pragma unroll
  for (int qt = 0; qt < 2; qt++){
    aq[qt][0] = *(const short8*)&Qh[(size_t)(qbase + qt*16 + ln) * HD + quad*8];
    aq[qt][1] = *(const short8*)&Qh[(size_t)(qbase + qt*16 + ln) * HD + 32 + quad*8];
  }

  floatx4 o[2][4] = {};
  float l_i[2][4] = {};
  float* Pf = &Plf[wid][0];

  // per-lane K/V base pointers (row fixed per lane, chunk offset varies)
  const u16* Krow = Kh + (size_t)ln * HD + quad * 8;          // + (key0+j*16)*HD, +32
  const u16* Vrow = Vh + (size_t)ln * TT + quad * 8;          // + n*16*TT + key0, +32

  const int nch_w = ((qbase + 31) >> 6) + 1;        // exact per-wave chunk count
  for (int ch = 0; ch < nch_w; ++ch){
    const int key0 = ch * 64;
    const bool act0 = (key0 <= qbase + 15);         // qt=0 tile not fully masked
    short8 pk0[2], pk1[2];                          // PV A-frags (key halves) per qt
    #pragma unroll
    for (int qt = 0; qt < 2; qt++){
      if (qt == 0 && !act0) continue;
      const int qt0 = qbase + qt*16;
      // S = Q K^T, K fragments straight from global (L1/L2-resident)
      floatx4 z[4];
      #pragma unroll
      for (int j = 0; j < 4; j++){
        const u16* kp = Krow + (size_t)(key0 + j*16) * HD;
        const short8 kb0 = *(const short8*)kp;
        const short8 kb1 = *(const short8*)(kp + 32);
        floatx4 zz = {0.0f, 0.0f, 0.0f, 0.0f};
        zz = __builtin_amdgcn_mfma_f32_16x16x32_bf16(aq[qt][0], kb0, zz, 0, 0, 0);
        zz = __builtin_amdgcn_mfma_f32_16x16x32_bf16(aq[qt][1], kb1, zz, 0, 0, 0);
        z[j] = zz;
      }
      if (key0 + 63 > qt0){                         // near-diagonal: apply causal mask
        #pragma unroll
        for (int j = 0; j < 4; j++)
          #pragma unroll
          for (int rr = 0; rr < 4; rr++){
            const int key = key0 + j*16 + ln;
            const int t   = qt0 + quad*4 + rr;
            if (key > t) z[j][rr] = NEGINF;
          }
      }
      // p = exp(s), fixed m=0; raw f32 to per-wave LDS (stride 68: bank-balanced)
      #pragma unroll
      for (int j = 0; j < 4; j++)
        #pragma unroll
        for (int rr = 0; rr < 4; rr++){
          const float p = __expf(z[j][rr]);
          l_i[qt][rr] += p;
          Pf[(quad*4 + rr) * 68 + j*16 + ln] = p;
        }
      asm volatile("s_waitcnt lgkmcnt(0)" ::: "memory");  // in-wave LDS RAW (DS ops in-order)
      pk0[qt] = cvt8(&Pf[ln * 68 + quad*8]);              // keys 0..31 A-frag
      pk1[qt] = cvt8(&Pf[ln * 68 + 32 + quad*8]);         // keys 32..63 A-frag
    }
    // PV: V^T fragments straight from global; read once, both q-tiles
    #pragma unroll
    for (int n = 0; n < 4; n++){
      const u16* vp = Vrow + (size_t)(n*16) * TT + key0;
      const short8 vb0 = *(const short8*)vp;
      const short8 vb1 = *(const short8*)(vp + 32);
      if (act0){
        o[0][n] = __builtin_amdgcn_mfma_f32_16x16x32_bf16(pk0[0], vb0, o[0][n], 0, 0, 0);
        o[0][n] = __builtin_amdgcn_mfma_f32_16x16x32_bf16(pk1[0], vb1, o[0][n], 0, 0, 0);
      }
      o[1][n] = __builtin_amdgcn_mfma_f32_16x16x32_bf16(pk0[1], vb0, o[1][n], 0, 0, 0);
      o[1][n] = __builtin_amdgcn_mfma_f32_16x16x32_bf16(pk1[1], vb1, o[1][n], 0, 0, 0);
    }
  }

  // reduce l over the quad's 16 lanes (once, after the loop)
  #pragma unroll
  for (int qt = 0; qt < 2; qt++)
    #pragma unroll
    for (int rr = 0; rr < 4; rr++){
      float rs = l_i[qt][rr];
      #pragma unroll
      for (int off = 1; off < 16; off <<= 1) rs += __shfl_xor(rs, off);
      l_i[qt][rr] = rs;
    }

  // epilogue: AO[b][t][h*64+d]
  #pragma unroll
  for (int qt = 0; qt < 2; qt++)
    #pragma unroll
    for (int n = 0; n < 4; n++)
      #pragma unroll
      for (int rr = 0; rr < 4; rr++){
        const int t = qbase + qt*16 + quad*4 + rr;
        const float inv_l = 1.0f / fmaxf(l_i[qt][rr], 1e-20f);
        AO[(size_t)(b_ * TT + t) * HIDDEN + h * HD + n*16 + ln] = f2bf(o[qt][n][rr] * inv_l);
      }
}

// ---------------- GEMM2: out = AO @ Wproj + bproj -> fp32 out (round-0) ----------------
__global__ void gemm_proj(const u16* __restrict__ A, const u16* __restrict__ WT,
                          const float* __restrict__ bias, float* __restrict__ out)
{
  __shared__ alignas(16) u16 As[128 * 32];
  __shared__ alignas(16) u16 Bs[128 * 32];
  const int tid = threadIdx.x;
  const int wid = tid >> 6, lane = tid & 63;
  const int quad = lane >> 4, ln = lane & 15;
  const int row0 = blockIdx.y * 128, col0 = blockIdx.x * 128;
  const int wm = (wid >> 1) * 64, wn = (wid & 1) * 64;
  floatx4 acc[4][4] = {};

  const int sr = tid >> 2, sk = (tid & 3) * 8;

  for (int kk = 0; kk < 32; ++kk){
    const int k0 = kk * 32;
    __syncthreads();
    load_lds16(&A [(size_t)(row0 + sr      ) * 1024 + k0 + sk], &As[(size_t)(tid      ) * 8]);
    load_lds16(&A [(size_t)(row0 + sr + 64 ) * 1024 + k0 + sk], &As[(size_t)(tid + 256) * 8]);
    load_lds16(&WT[(size_t)(col0 + sr      ) * 1024 + k0 + sk], &Bs[(size_t)(tid      ) * 8]);
    load_lds16(&WT[(size_t)(col0 + sr + 64 ) * 1024 + k0 + sk], &Bs[(size_t)(tid + 256) * 8]);
    __syncthreads();
    short8 a[4], b[4];
    #pragma unroll
    for (int i = 0; i < 4; i++) a[i] = *(const short8*)&As[(wm + i*16 + ln) * 32 + quad * 8];
    #pragma unroll
    for (int j = 0; j < 4; j++) b[j] = *(const short8*)&Bs[(wn + j*16 + ln) * 32 + quad * 8];
    #pragma unroll
    for (int i = 0; i < 4; i++)
      #pragma unroll
      for (int j = 0; j < 4; j++)
        acc[i][j] = __builtin_amdgcn_mfma_f32_16x16x32_bf16(a[i], b[j], acc[i][j], 0, 0, 0);
  }

  float bs[4];
  #pragma unroll
  for (int j = 0; j < 4; j++) bs[j] = bias[col0 + wn + j*16 + ln];
  #pragma unroll
  for (int i = 0; i < 4; i++)
    #pragma unroll
    for (int rr = 0; rr < 4; rr++){
      const int rowg = row0 + wm + i*16 + quad*4 + rr;
      #pragma unroll
      for (int j = 0; j < 4; j++)
        out[(size_t)rowg * HIDDEN + col0 + wn + j*16 + ln] = acc[i][j][rr] + bs[j];
    }
}

extern "C" void kernel_launch(void* const* d_in, const int* in_sizes, int n_in,
                              void* d_out, int out_size, void* d_ws, size_t ws_size,
                              hipStream_t stream)
{
  const float* x     = (const float*)d_in[0];
  const float* rnn   = (const float*)d_in[1];
  const float* Wqkv  = (const float*)d_in[2];
  const float* bqkv  = (const float*)d_in[3];
  const float* Wproj = (const float*)d_in[4];
  const float* bproj = (const float*)d_in[5];
  float* out = (float*)d_out;

  // ---- workspace layout (byte offsets, 16B-aligned), ~93 MB ----
  char* ws = (char*)d_ws;
  size_t off = 0;
  float* ropeC  = (float*)(ws + off); off += (size_t)TT * 32 * 4;
  float* ropeS  = (float*)(ws + off); off += (size_t)TT * 32 * 4;
  u16*   xN     = (u16*)(ws + off);   off += (size_t)MM * HIDDEN * 2;
  u16*   WqkvT  = (u16*)(ws + off);   off += (size_t)NQKV * HIDDEN * 2;
  u16*   WprojT = (u16*)(ws + off);   off += (size_t)HIDDEN * HIDDEN * 2;
  u16*   Qb     = (u16*)(ws + off);   off += (size_t)MM * HIDDEN * 2;
  u16*   Kb     = (u16*)(ws + off);   off += (size_t)MM * HIDDEN * 2;
  u16*   Vtg    = (u16*)(ws + off);   off += (size_t)MM * HIDDEN * 2;   // V^T [bh][d][t]
  u16*   AO     = (u16*)(ws + off);   off += (size_t)MM * HIDDEN * 2;

  prep<<<PREP_BLKS, 256, 0, stream>>>(x, xN, Wqkv, WqkvT, Wproj, WprojT,
                                      ropeC, ropeS, rnn, out);
  gemm_qkv<<<dim3(NQKV / 128, MM / 128), 256, 0, stream>>>(xN, WqkvT, bqkv, ropeC, ropeS, Qb, Kb, Vtg);
  attn<<<dim3(BB * NHEAD, 16), 256, 0, stream>>>(Qb, Kb, Vtg, AO);
  gemm_proj<<<dim3(HIDDEN / 128, MM / 128), 256, 0, stream>>>(AO, WprojT, bproj, out);
}

// Round 10
// 270.504 us; speedup vs baseline: 1.5167x; 1.5167x over previous
//
#include <hip/hip_runtime.h>
#include <cstdint>
#include <cstddef>
#include <math.h>

typedef unsigned short u16;
typedef __attribute__((ext_vector_type(8))) short short8;
typedef __attribute__((ext_vector_type(4))) float floatx4;

#define HIDDEN 1024
#define NHEAD 16
#define HD 64
#define BB 4
#define TT 2048
#define MM (BB*TT)      /* 8192 rows of x */
#define NQKV 3072
#define NEGINF (-30000.0f)
#define GFENCE() asm volatile("" ::: "memory")

__device__ inline u16 f2bf(float f){
  union { float f; unsigned u; } v; v.f = f;
  unsigned r = v.u + 0x7FFFu + ((v.u >> 16) & 1u);
  return (u16)(r >> 16);
}
__device__ inline void load_lds16(const void* g, void* l){
  __builtin_amdgcn_global_load_lds((const __attribute__((address_space(1))) void*)g,
                                   (__attribute__((address_space(3))) void*)l,
                                   16, 0, 0);
}
// 8 consecutive f32 -> bf16x8 via hardware v_cvt_pk_bf16_f32 (RNE), 4 ops
__device__ inline short8 cvt8(const float* p){
  const floatx4 a = *(const floatx4*)p;
  const floatx4 b = *(const floatx4*)(p + 4);
  union { short8 s; unsigned u[4]; } r;
  asm("v_cvt_pk_bf16_f32 %0, %1, %2" : "=v"(r.u[0]) : "v"(a[0]), "v"(a[1]));
  asm("v_cvt_pk_bf16_f32 %0, %1, %2" : "=v"(r.u[1]) : "v"(a[2]), "v"(a[3]));
  asm("v_cvt_pk_bf16_f32 %0, %1, %2" : "=v"(r.u[2]) : "v"(b[0]), "v"(b[1]));
  asm("v_cvt_pk_bf16_f32 %0, %1, %2" : "=v"(r.u[3]) : "v"(b[2]), "v"(b[3]));
  return r.s;
}

// ---------------- fused prep: convert_x + transpose(Wqkv) + transpose(Wproj) + rope + tail ----
#define PREP_CONV_BLKS  4096                 /* 8192*1024/(256*8) */
#define PREP_TQKV_BLKS  (96*32)              /* (3072/32)*(1024/32) */
#define PREP_TPROJ_BLKS (32*32)
#define PREP_ROPE_BLKS  (TT*32/256)          /* 256 */
#define PREP_TAIL_BLKS  ((BB*HIDDEN+255)/256)/* 16 */
#define PREP_BLKS (PREP_CONV_BLKS + PREP_TQKV_BLKS + PREP_TPROJ_BLKS + PREP_ROPE_BLKS + PREP_TAIL_BLKS)

__global__ void prep(const float* __restrict__ x, u16* __restrict__ xN,
                     const float* __restrict__ Wqkv, u16* __restrict__ WqkvT,
                     const float* __restrict__ Wproj, u16* __restrict__ WprojT,
                     float* __restrict__ ropeC, float* __restrict__ ropeS,
                     const float* __restrict__ rnn, float* __restrict__ out)
{
  __shared__ alignas(16) u16 tile[32][33];
  int blk = blockIdx.x;
  const int tid = threadIdx.x;

  if (blk < PREP_CONV_BLKS){                 // ---- convert_x ----
    const int i = (blk * 256 + tid) * 8;
    #pragma unroll
    for (int u = 0; u < 8; u++) xN[i + u] = f2bf(x[i + u]);
    return;
  }
  blk -= PREP_CONV_BLKS;
  if (blk < PREP_TQKV_BLKS + PREP_TPROJ_BLKS){   // ---- transposes ----
    const float* in; u16* outp; int R, C, c0, r0;
    if (blk < PREP_TQKV_BLKS){
      in = Wqkv; outp = WqkvT; R = HIDDEN; C = NQKV;
      c0 = (blk % 96) * 32; r0 = (blk / 96) * 32;
    } else {
      const int b2 = blk - PREP_TQKV_BLKS;
      in = Wproj; outp = WprojT; R = HIDDEN; C = HIDDEN;
      c0 = (b2 % 32) * 32; r0 = (b2 / 32) * 32;
    }
    const int tx = tid & 31, ty = tid >> 5;  // 32 x 8
    for (int i = ty; i < 32; i += 8)
      tile[i][tx] = f2bf(in[(size_t)(r0 + i) * C + c0 + tx]);
    __syncthreads();
    for (int i = ty; i < 32; i += 8) outp[(size_t)(c0 + i) * R + r0 + tx] = tile[tx][i];
    return;
  }
  blk -= PREP_TQKV_BLKS + PREP_TPROJ_BLKS;
  if (blk < PREP_ROPE_BLKS){                 // ---- rope tables ----
    const int idx = blk * 256 + tid;         // t*32 + f
    const int t = idx >> 5, f = idx & 31;
    const float inv = powf(10000.0f, -(float)f * (1.0f / 32.0f));
    const float ang = (float)t * inv;
    ropeC[idx] = cosf(ang);
    ropeS[idx] = sinf(ang);
    return;
  }
  blk -= PREP_ROPE_BLKS;
  {                                          // ---- rnn_state tail ----
    const int i = blk * 256 + tid;
    if (i < BB * HIDDEN) out[(size_t)MM * HIDDEN + i] = rnn[i];
  }
}

// ---------------- GEMM1 v2: 256x128 tile, BK=64, dbuf + counted vmcnt + LDS swizzle ----------
// 512 threads / 8 waves; per-wave 64x64 output (acc[4][4], epilogue identical to round-4).
// K-loop: COMPUTE(cur) -> lgkmcnt(0) -> barrier -> STAGE(t+2 into cur) -> vmcnt(6) -> barrier.
// Loads for tile t+1 stay in flight across the whole of tile t's compute (never vmcnt(0)
// in steady state). LDS rows are XOR-swizzled (col ^= (row&3)<<4 in u16) on BOTH the
// stage-source and the ds_read side -> 4-way (structural b128 floor) instead of 16-way.
// LDS: As 64KB + Bs 32KB + VTx 24KB = 120KB -> 1 block/CU, grid 768 = exactly 3 rounds.
__global__ void __launch_bounds__(512, 2)
gemm_qkv(const u16* __restrict__ X, const u16* __restrict__ WT,
         const float* __restrict__ bias,
         const float* __restrict__ ropeC, const float* __restrict__ ropeS,
         u16* __restrict__ Qb, u16* __restrict__ Kb, u16* __restrict__ Vtg)
{
  __shared__ alignas(16) u16 As[2][256 * 64];
  __shared__ alignas(16) u16 Bs[2][128 * 64];
  __shared__ alignas(16) u16 VTx[8][64 * 24];   // per-wave V-transpose tile ([d][t16], pad 24)
  const int tid = threadIdx.x;
  const int wid = tid >> 6, lane = tid & 63;
  const int quad = lane >> 4, ln = lane & 15;
  const int row0 = blockIdx.y * 256, col0 = blockIdx.x * 128;
  const int wm = (wid >> 1) * 64, wn = (wid & 1) * 64;
  floatx4 acc[4][4] = {};

#define QSTAGE(buf, t) do {                                                                  \
    const int k0_ = (t) * 64;                                                                \
    _Pragma("unroll")                                                                        \
    for (int i_ = 0; i_ < 4; i_++){                                                          \
      const int idx_ = i_ * 512 + tid; const int r_ = idx_ >> 3, c8_ = idx_ & 7;             \
      load_lds16(&X[(size_t)(row0 + r_) * 1024 + k0_ + ((c8_*8) ^ ((r_&3)<<4))],             \
                 &As[buf][(size_t)idx_ * 8]);                                                \
    }                                                                                        \
    _Pragma("unroll")                                                                        \
    for (int i_ = 0; i_ < 2; i_++){                                                          \
      const int idx_ = i_ * 512 + tid; const int r_ = idx_ >> 3, c8_ = idx_ & 7;             \
      load_lds16(&WT[(size_t)(col0 + r_) * 1024 + k0_ + ((c8_*8) ^ ((r_&3)<<4))],            \
                 &Bs[buf][(size_t)idx_ * 8]);                                                \
    }                                                                                        \
  } while (0)

#define QCOMPUTE(buf) do {                                                                   \
    short8 b0[4], b1[4];                                                                     \
    _Pragma("unroll")                                                                        \
    for (int n = 0; n < 4; n++){                                                             \
      const int br = wn + n*16 + ln; const int sw = (br & 3) << 4;                           \
      b0[n] = *(const short8*)&Bs[buf][br*64 + ((quad*8) ^ sw)];                             \
      b1[n] = *(const short8*)&Bs[buf][br*64 + ((32 + quad*8) ^ sw)];                        \
    }                                                                                        \
    _Pragma("unroll")                                                                        \
    for (int m = 0; m < 4; m++){                                                             \
      const int ar = wm + m*16 + ln; const int sw = (ar & 3) << 4;                           \
      const short8 a0 = *(const short8*)&As[buf][ar*64 + ((quad*8) ^ sw)];                   \
      const short8 a1 = *(const short8*)&As[buf][ar*64 + ((32 + quad*8) ^ sw)];              \
      _Pragma("unroll")                                                                      \
      for (int n = 0; n < 4; n++){                                                           \
        acc[m][n] = __builtin_amdgcn_mfma_f32_16x16x32_bf16(a0, b0[n], acc[m][n], 0, 0, 0);  \
        acc[m][n] = __builtin_amdgcn_mfma_f32_16x16x32_bf16(a1, b1[n], acc[m][n], 0, 0, 0);  \
      }                                                                                      \
    }                                                                                        \
  } while (0)

  // prologue: tiles 0,1 in flight; wait tile 0 (6 of 12 outstanding), barrier
  QSTAGE(0, 0);
  QSTAGE(1, 1);
  asm volatile("s_waitcnt vmcnt(6)" ::: "memory");
  __builtin_amdgcn_s_barrier();
  GFENCE();

  #pragma unroll 2
  for (int t = 0; t < 16; ++t){
    const int cur = t & 1;
    QCOMPUTE(cur);
    GFENCE();
    asm volatile("s_waitcnt lgkmcnt(0)" ::: "memory");   // my reads of buf[cur] retired
    __builtin_amdgcn_s_barrier();                        // A: all waves done reading buf[cur]
    GFENCE();
    if (t < 14){
      QSTAGE(cur, t + 2);                                // refill the buffer just freed
      asm volatile("s_waitcnt vmcnt(6)" ::: "memory");   // tile t+1's 6 loads landed
      __builtin_amdgcn_s_barrier();                      // B: t+1 ready for everyone
      GFENCE();
    } else if (t == 14){
      asm volatile("s_waitcnt vmcnt(0)" ::: "memory");   // drain tile 15 (tail only)
      __builtin_amdgcn_s_barrier();
      GFENCE();
    }
  }

  // epilogue: C-layout col = lane&15, row = quad*4 + reg  (identical to round-4, i->m)
  const int wcol0 = col0 + wn;            // 64-aligned -> single (which, head) per wave
  const int which = wcol0 >> 10;          // 0=q 1=k 2=v  (block-uniform per wave)
  const int h = (wcol0 & 1023) >> 6;
  float bs[4];
  #pragma unroll
  for (int j = 0; j < 4; j++) bs[j] = bias[wcol0 + j*16 + ln];

  if (which < 2){
    #pragma unroll
    for (int m = 0; m < 4; m++){
      #pragma unroll
      for (int rr = 0; rr < 4; rr++){
        const int rowg = row0 + wm + m*16 + quad*4 + rr;
        const int b_ = rowg >> 11, t = rowg & 2047;
        u16* op = (which == 0 ? Qb : Kb) + ((size_t)(b_ * NHEAD + h) * TT + t) * HD;
        #pragma unroll
        for (int j = 0; j < 2; j++){
          const int f = j*16 + ln;
          const float cs = ropeC[t * 32 + f];
          const float sn = ropeS[t * 32 + f];
          const float x1 = acc[m][j  ][rr] + bs[j  ];
          const float x2 = acc[m][j+2][rr] + bs[j+2];
          float y1 = x1 * cs - x2 * sn;
          float y2 = x1 * sn + x2 * cs;
          if (which == 0){ y1 *= 0.125f; y2 *= 0.125f; }
          op[f]      = f2bf(y1);
          op[f + 32] = f2bf(y2);
        }
      }
    }
  } else {
    // V: per-wave LDS transpose in 16-t chunks -> coalesced 16B stores along t.
    #pragma unroll
    for (int m = 0; m < 4; m++){
      #pragma unroll
      for (int j = 0; j < 4; j++)
        #pragma unroll
        for (int rr = 0; rr < 4; rr++)
          VTx[wid][(j*16 + ln) * 24 + quad*4 + rr] = f2bf(acc[m][j][rr] + bs[j]);
      asm volatile("s_waitcnt lgkmcnt(0)" ::: "memory");   // cross-lane in-wave LDS RAW
      const int d = lane;                                   // 0..63
      const short8 v0 = *(const short8*)&VTx[wid][d * 24 + 0];
      const short8 v1 = *(const short8*)&VTx[wid][d * 24 + 8];
      const int rowg = row0 + wm + m*16;
      const int b_ = rowg >> 11, t0 = rowg & 2047;
      u16* vp = &Vtg[((size_t)(b_ * NHEAD + h) * HD + d) * TT + t0];
      *(short8*)&vp[0] = v0;
      *(short8*)&vp[8] = v1;
      asm volatile("s_waitcnt lgkmcnt(0)" ::: "memory");   // reads done before next chunk's writes
    }
  }
#undef QSTAGE
#undef QCOMPUTE
}

// ---------------- flash attention v10 (round-8 measured best, verbatim revert) ----------------
__global__ void __launch_bounds__(256, 3)
attn(const u16* __restrict__ Qb, const u16* __restrict__ Kb,
     const u16* __restrict__ Vtg, u16* __restrict__ AO)
{
  const int bh = blockIdx.x, tbi = 15 - (int)blockIdx.y;
  const int tid = threadIdx.x;
  const int wid = tid >> 6, lane = tid & 63;
  const int quad = lane >> 4, ln = lane & 15;

  __shared__ alignas(16) u16 Kl2[2][64 * 72];       // [buf][key][d], pad 72
  __shared__ alignas(16) u16 Vt2[2][64 * 72];       // [buf][d][key], pad 72
  __shared__ alignas(16) float Plf[4][16 * 68];     // per-wave f32 P tile, stride 68 (bank-balanced)

  const u16* Qh = Qb  + (size_t)bh * TT * HD;
  const u16* Kh = Kb  + (size_t)bh * TT * HD;
  const u16* Vh = Vtg + (size_t)bh * HD * TT;       // [d][t]
  const int b_ = bh >> 4, h = bh & 15;

  const int qbase = tbi * 128 + wid * 32;           // wave owns rows [qbase, qbase+31]

  short8 aq[2][2];
  #pragma unroll
  for (int qt = 0; qt < 2; qt++){
    aq[qt][0] = *(const short8*)&Qh[(size_t)(qbase + qt*16 + ln) * HD + quad*8];
    aq[qt][1] = *(const short8*)&Qh[(size_t)(qbase + qt*16 + ln) * HD + 32 + quad*8];
  }

  floatx4 o[2][4] = {};
  float l_i[2][4] = {};
  float* Pf = &Plf[wid][0];

  // staging geometry: thread covers rows pr and pr+32, 8 threads x 16B per row
  const int pr = tid >> 3, pc = (tid & 7) * 8;
  short8 kpre0, kpre1, vpre0, vpre1;

  const int nch = 2 * (tbi + 1);

  // prologue: chunk 0 -> regs -> buf0
  kpre0 = *(const short8*)&Kh[(size_t)(pr     ) * HD + pc];
  kpre1 = *(const short8*)&Kh[(size_t)(pr + 32) * HD + pc];
  vpre0 = *(const short8*)&Vh[(size_t)(pr     ) * TT + pc];
  vpre1 = *(const short8*)&Vh[(size_t)(pr + 32) * TT + pc];
  *(short8*)&Kl2[0][(pr     ) * 72 + pc] = kpre0;
  *(short8*)&Kl2[0][(pr + 32) * 72 + pc] = kpre1;
  *(short8*)&Vt2[0][(pr     ) * 72 + pc] = vpre0;
  *(short8*)&Vt2[0][(pr + 32) * 72 + pc] = vpre1;
  __syncthreads();

  int cur = 0;
  for (int ch = 0; ch < nch; ++ch){
    const int key0 = ch * 64;
    // load-early: next chunk's global loads go in flight over this chunk's compute
    if (ch + 1 < nch){
      const int nk0 = key0 + 64;
      kpre0 = *(const short8*)&Kh[(size_t)(nk0 + pr     ) * HD + pc];
      kpre1 = *(const short8*)&Kh[(size_t)(nk0 + pr + 32) * HD + pc];
      vpre0 = *(const short8*)&Vh[(size_t)(pr     ) * TT + nk0 + pc];
      vpre1 = *(const short8*)&Vh[(size_t)(pr + 32) * TT + nk0 + pc];
    }

    // wave-uniform skip: chunk entirely above this wave's diagonal
    if (key0 <= qbase + 31){
      const u16* Kl = Kl2[cur];
      const u16* Vt = Vt2[cur];
      const bool act0 = (key0 <= qbase + 15);     // qt=0 tile not fully masked
      short8 pk0[2], pk1[2];                      // PV A-frags (key halves) per qt
      #pragma unroll
      for (int qt = 0; qt < 2; qt++){
        if (qt == 0 && !act0) continue;
        const int qt0 = qbase + qt*16;
        // S = Q K^T for this q-tile
        floatx4 z[4];
        #pragma unroll
        for (int j = 0; j < 4; j++){
          const short8 kb0 = *(const short8*)&Kl[(j*16 + ln) * 72 + quad*8];
          const short8 kb1 = *(const short8*)&Kl[(j*16 + ln) * 72 + 32 + quad*8];
          floatx4 zz = {0.0f, 0.0f, 0.0f, 0.0f};
          zz = __builtin_amdgcn_mfma_f32_16x16x32_bf16(aq[qt][0], kb0, zz, 0, 0, 0);
          zz = __builtin_amdgcn_mfma_f32_16x16x32_bf16(aq[qt][1], kb1, zz, 0, 0, 0);
          z[j] = zz;
        }
        if (key0 + 63 > qt0){                     // near-diagonal: apply causal mask
          #pragma unroll
          for (int j = 0; j < 4; j++)
            #pragma unroll
            for (int rr = 0; rr < 4; rr++){
              const int key = key0 + j*16 + ln;
              const int t   = qt0 + quad*4 + rr;
              if (key > t) z[j][rr] = NEGINF;
            }
        }
        // p = exp(s), fixed m=0; store RAW f32 to LDS (stride 68: bank-balanced)
        #pragma unroll
        for (int j = 0; j < 4; j++)
          #pragma unroll
          for (int rr = 0; rr < 4; rr++){
            const float p = __expf(z[j][rr]);
            l_i[qt][rr] += p;
            Pf[(quad*4 + rr) * 68 + j*16 + ln] = p;
          }
        asm volatile("s_waitcnt lgkmcnt(0)" ::: "memory");  // cross-lane in-wave LDS RAW
        pk0[qt] = cvt8(&Pf[ln * 68 + quad*8]);              // keys 0..31 A-frag
        pk1[qt] = cvt8(&Pf[ln * 68 + 32 + quad*8]);         // keys 32..63 A-frag
      }
      // PV: vb read once, both q-tiles
      #pragma unroll
      for (int n = 0; n < 4; n++){
        const short8 vb0 = *(const short8*)&Vt[(n*16 + ln) * 72 + quad*8];
        const short8 vb1 = *(const short8*)&Vt[(n*16 + ln) * 72 + 32 + quad*8];
        if (act0){
          o[0][n] = __builtin_amdgcn_mfma_f32_16x16x32_bf16(pk0[0], vb0, o[0][n], 0, 0, 0);
          o[0][n] = __builtin_amdgcn_mfma_f32_16x16x32_bf16(pk1[0], vb1, o[0][n], 0, 0, 0);
        }
        o[1][n] = __builtin_amdgcn_mfma_f32_16x16x32_bf16(pk0[1], vb0, o[1][n], 0, 0, 0);
        o[1][n] = __builtin_amdgcn_mfma_f32_16x16x32_bf16(pk1[1], vb1, o[1][n], 0, 0, 0);
      }
    }

    // write-late: commit prefetched chunk to the OTHER buffer (vmcnt waits here,
    // after compute). Safe: buf[cur^1] was last read in iter ch-1, sealed by its barrier.
    if (ch + 1 < nch){
      *(short8*)&Kl2[cur ^ 1][(pr     ) * 72 + pc] = kpre0;
      *(short8*)&Kl2[cur ^ 1][(pr + 32) * 72 + pc] = kpre1;
      *(short8*)&Vt2[cur ^ 1][(pr     ) * 72 + pc] = vpre0;
      *(short8*)&Vt2[cur ^ 1][(pr + 32) * 72 + pc] = vpre1;
    }
    __syncthreads();                              // ONE barrier per chunk
    cur ^= 1;
  }

  // reduce l over the quad's 16 lanes (once, after the loop)
  #pragma unroll
  for (int qt = 0; qt < 2; qt++)
    #pragma unroll
    for (int rr = 0; rr < 4; rr++){
      float rs = l_i[qt][rr];
      #pragma unroll
      for (int off = 1; off < 16; off <<= 1) rs += __shfl_xor(rs, off);
      l_i[qt][rr] = rs;
    }

  // epilogue: AO[b][t][h*64+d]
  #pragma unroll
  for (int qt = 0; qt < 2; qt++)
    #pragma unroll
    for (int n = 0; n < 4; n++)
      #pragma unroll
      for (int rr = 0; rr < 4; rr++){
        const int t = qbase + qt*16 + quad*4 + rr;
        const float inv_l = 1.0f / fmaxf(l_i[qt][rr], 1e-20f);
        AO[(size_t)(b_ * TT + t) * HIDDEN + h * HD + n*16 + ln] = f2bf(o[qt][n][rr] * inv_l);
      }
}

// ---------------- GEMM2: out = AO @ Wproj + bproj -> fp32 out (round-0) ----------------
__global__ void gemm_proj(const u16* __restrict__ A, const u16* __restrict__ WT,
                          const float* __restrict__ bias, float* __restrict__ out)
{
  __shared__ alignas(16) u16 As[128 * 32];
  __shared__ alignas(16) u16 Bs[128 * 32];
  const int tid = threadIdx.x;
  const int wid = tid >> 6, lane = tid & 63;
  const int quad = lane >> 4, ln = lane & 15;
  const int row0 = blockIdx.y * 128, col0 = blockIdx.x * 128;
  const int wm = (wid >> 1) * 64, wn = (wid & 1) * 64;
  floatx4 acc[4][4] = {};

  const int sr = tid >> 2, sk = (tid & 3) * 8;

  for (int kk = 0; kk < 32; ++kk){
    const int k0 = kk * 32;
    __syncthreads();
    load_lds16(&A [(size_t)(row0 + sr      ) * 1024 + k0 + sk], &As[(size_t)(tid      ) * 8]);
    load_lds16(&A [(size_t)(row0 + sr + 64 ) * 1024 + k0 + sk], &As[(size_t)(tid + 256) * 8]);
    load_lds16(&WT[(size_t)(col0 + sr      ) * 1024 + k0 + sk], &Bs[(size_t)(tid      ) * 8]);
    load_lds16(&WT[(size_t)(col0 + sr + 64 ) * 1024 + k0 + sk], &Bs[(size_t)(tid + 256) * 8]);
    __syncthreads();
    short8 a[4], b[4];
    #pragma unroll
    for (int i = 0; i < 4; i++) a[i] = *(const short8*)&As[(wm + i*16 + ln) * 32 + quad * 8];
    #pragma unroll
    for (int j = 0; j < 4; j++) b[j] = *(const short8*)&Bs[(wn + j*16 + ln) * 32 + quad * 8];
    #pragma unroll
    for (int i = 0; i < 4; i++)
      #pragma unroll
      for (int j = 0; j < 4; j++)
        acc[i][j] = __builtin_amdgcn_mfma_f32_16x16x32_bf16(a[i], b[j], acc[i][j], 0, 0, 0);
  }

  float bs[4];
  #pragma unroll
  for (int j = 0; j < 4; j++) bs[j] = bias[col0 + wn + j*16 + ln];
  #pragma unroll
  for (int i = 0; i < 4; i++)
    #pragma unroll
    for (int rr = 0; rr < 4; rr++){
      const int rowg = row0 + wm + i*16 + quad*4 + rr;
      #pragma unroll
      for (int j = 0; j < 4; j++)
        out[(size_t)rowg * HIDDEN + col0 + wn + j*16 + ln] = acc[i][j][rr] + bs[j];
    }
}

extern "C" void kernel_launch(void* const* d_in, const int* in_sizes, int n_in,
                              void* d_out, int out_size, void* d_ws, size_t ws_size,
                              hipStream_t stream)
{
  const float* x     = (const float*)d_in[0];
  const float* rnn   = (const float*)d_in[1];
  const float* Wqkv  = (const float*)d_in[2];
  const float* bqkv  = (const float*)d_in[3];
  const float* Wproj = (const float*)d_in[4];
  const float* bproj = (const float*)d_in[5];
  float* out = (float*)d_out;

  // ---- workspace layout (byte offsets, 16B-aligned), ~93 MB ----
  char* ws = (char*)d_ws;
  size_t off = 0;
  float* ropeC  = (float*)(ws + off); off += (size_t)TT * 32 * 4;
  float* ropeS  = (float*)(ws + off); off += (size_t)TT * 32 * 4;
  u16*   xN     = (u16*)(ws + off);   off += (size_t)MM * HIDDEN * 2;
  u16*   WqkvT  = (u16*)(ws + off);   off += (size_t)NQKV * HIDDEN * 2;
  u16*   WprojT = (u16*)(ws + off);   off += (size_t)HIDDEN * HIDDEN * 2;
  u16*   Qb     = (u16*)(ws + off);   off += (size_t)MM * HIDDEN * 2;
  u16*   Kb     = (u16*)(ws + off);   off += (size_t)MM * HIDDEN * 2;
  u16*   Vtg    = (u16*)(ws + off);   off += (size_t)MM * HIDDEN * 2;   // V^T [bh][d][t]
  u16*   AO     = (u16*)(ws + off);   off += (size_t)MM * HIDDEN * 2;

  prep<<<PREP_BLKS, 256, 0, stream>>>(x, xN, Wqkv, WqkvT, Wproj, WprojT,
                                      ropeC, ropeS, rnn, out);
  gemm_qkv<<<dim3(NQKV / 128, MM / 256), 512, 0, stream>>>(xN, WqkvT, bqkv, ropeC, ropeS, Qb, Kb, Vtg);
  attn<<<dim3(BB * NHEAD, 16), 256, 0, stream>>>(Qb, Kb, Vtg, AO);
  gemm_proj<<<dim3(HIDDEN / 128, MM / 128), 256, 0, stream>>>(AO, WprojT, bproj, out);
}

// Round 11
// 263.887 us; speedup vs baseline: 1.5547x; 1.0251x over previous
//
#include <hip/hip_runtime.h>
#include <cstdint>
#include <cstddef>
#include <math.h>

typedef unsigned short u16;
typedef __attribute__((ext_vector_type(8))) short short8;
typedef __attribute__((ext_vector_type(4))) float floatx4;

#define HIDDEN 1024
#define NHEAD 16
#define HD 64
#define BB 4
#define TT 2048
#define MM (BB*TT)      /* 8192 rows of x */
#define NQKV 3072
#define NEGINF (-30000.0f)

__device__ inline u16 f2bf(float f){
  union { float f; unsigned u; } v; v.f = f;
  unsigned r = v.u + 0x7FFFu + ((v.u >> 16) & 1u);
  return (u16)(r >> 16);
}
__device__ inline void load_lds16(const void* g, void* l){
  __builtin_amdgcn_global_load_lds((const __attribute__((address_space(1))) void*)g,
                                   (__attribute__((address_space(3))) void*)l,
                                   16, 0, 0);
}
// 8 consecutive f32 -> bf16x8 via hardware v_cvt_pk_bf16_f32 (RNE), 4 ops
__device__ inline short8 cvt8(const float* p){
  const floatx4 a = *(const floatx4*)p;
  const floatx4 b = *(const floatx4*)(p + 4);
  union { short8 s; unsigned u[4]; } r;
  asm("v_cvt_pk_bf16_f32 %0, %1, %2" : "=v"(r.u[0]) : "v"(a[0]), "v"(a[1]));
  asm("v_cvt_pk_bf16_f32 %0, %1, %2" : "=v"(r.u[1]) : "v"(a[2]), "v"(a[3]));
  asm("v_cvt_pk_bf16_f32 %0, %1, %2" : "=v"(r.u[2]) : "v"(b[0]), "v"(b[1]));
  asm("v_cvt_pk_bf16_f32 %0, %1, %2" : "=v"(r.u[3]) : "v"(b[2]), "v"(b[3]));
  return r.s;
}

// ---------------- fused prep: convert_x + transpose(Wqkv) + transpose(Wproj) + rope + tail ----
#define PREP_CONV_BLKS  4096                 /* 8192*1024/(256*8) */
#define PREP_TQKV_BLKS  (96*32)              /* (3072/32)*(1024/32) */
#define PREP_TPROJ_BLKS (32*32)
#define PREP_ROPE_BLKS  (TT*32/256)          /* 256 */
#define PREP_TAIL_BLKS  ((BB*HIDDEN+255)/256)/* 16 */
#define PREP_BLKS (PREP_CONV_BLKS + PREP_TQKV_BLKS + PREP_TPROJ_BLKS + PREP_ROPE_BLKS + PREP_TAIL_BLKS)

__global__ void prep(const float* __restrict__ x, u16* __restrict__ xN,
                     const float* __restrict__ Wqkv, u16* __restrict__ WqkvT,
                     const float* __restrict__ Wproj, u16* __restrict__ WprojT,
                     float* __restrict__ ropeC, float* __restrict__ ropeS,
                     const float* __restrict__ rnn, float* __restrict__ out)
{
  __shared__ alignas(16) u16 tile[32][33];
  int blk = blockIdx.x;
  const int tid = threadIdx.x;

  if (blk < PREP_CONV_BLKS){                 // ---- convert_x ----
    const int i = (blk * 256 + tid) * 8;
    #pragma unroll
    for (int u = 0; u < 8; u++) xN[i + u] = f2bf(x[i + u]);
    return;
  }
  blk -= PREP_CONV_BLKS;
  if (blk < PREP_TQKV_BLKS + PREP_TPROJ_BLKS){   // ---- transposes ----
    const float* in; u16* outp; int R, C, c0, r0;
    if (blk < PREP_TQKV_BLKS){
      in = Wqkv; outp = WqkvT; R = HIDDEN; C = NQKV;
      c0 = (blk % 96) * 32; r0 = (blk / 96) * 32;
    } else {
      const int b2 = blk - PREP_TQKV_BLKS;
      in = Wproj; outp = WprojT; R = HIDDEN; C = HIDDEN;
      c0 = (b2 % 32) * 32; r0 = (b2 / 32) * 32;
    }
    const int tx = tid & 31, ty = tid >> 5;  // 32 x 8
    for (int i = ty; i < 32; i += 8)
      tile[i][tx] = f2bf(in[(size_t)(r0 + i) * C + c0 + tx]);
    __syncthreads();
    for (int i = ty; i < 32; i += 8) outp[(size_t)(c0 + i) * R + r0 + tx] = tile[tx][i];
    return;
  }
  blk -= PREP_TQKV_BLKS + PREP_TPROJ_BLKS;
  if (blk < PREP_ROPE_BLKS){                 // ---- rope tables ----
    const int idx = blk * 256 + tid;         // t*32 + f
    const int t = idx >> 5, f = idx & 31;
    const float inv = powf(10000.0f, -(float)f * (1.0f / 32.0f));
    const float ang = (float)t * inv;
    ropeC[idx] = cosf(ang);
    ropeS[idx] = sinf(ang);
    return;
  }
  blk -= PREP_ROPE_BLKS;
  {                                          // ---- rnn_state tail ----
    const int i = blk * 256 + tid;
    if (i < BB * HIDDEN) out[(size_t)MM * HIDDEN + i] = rnn[i];
  }
}

// ---------------- GEMM1: qkv = x @ Wqkv + b, fused RoPE + head transpose ----------------
// (round-4 measured best: 78.5 us, 656 TF, 3 blocks/CU — reverted from round-10 deep pipe)
// V epilogue transposes through per-wave LDS for coalesced stores.
// Writes Q,K as [64 bh][2048 t][64 d] bf16 (Q pre-scaled 0.125), V as V^T [64 bh][64 d][2048 t].
__global__ void gemm_qkv(const u16* __restrict__ X, const u16* __restrict__ WT,
                         const float* __restrict__ bias,
                         const float* __restrict__ ropeC, const float* __restrict__ ropeS,
                         u16* __restrict__ Qb, u16* __restrict__ Kb, u16* __restrict__ Vtg)
{
  __shared__ alignas(16) u16 As[128 * 32];
  __shared__ alignas(16) u16 Bs[128 * 32];
  __shared__ alignas(16) u16 VTx[4][64 * 24];   // per-wave V-transpose tile ([d][t16], pad 24)
  const int tid = threadIdx.x;
  const int wid = tid >> 6, lane = tid & 63;
  const int quad = lane >> 4, ln = lane & 15;
  const int row0 = blockIdx.y * 128, col0 = blockIdx.x * 128;
  const int wm = (wid >> 1) * 64, wn = (wid & 1) * 64;
  floatx4 acc[4][4] = {};

  const int sr = tid >> 2, sk = (tid & 3) * 8;

  for (int kk = 0; kk < 32; ++kk){
    const int k0 = kk * 32;
    __syncthreads();
    load_lds16(&X [(size_t)(row0 + sr      ) * 1024 + k0 + sk], &As[(size_t)(tid      ) * 8]);
    load_lds16(&X [(size_t)(row0 + sr + 64 ) * 1024 + k0 + sk], &As[(size_t)(tid + 256) * 8]);
    load_lds16(&WT[(size_t)(col0 + sr      ) * 1024 + k0 + sk], &Bs[(size_t)(tid      ) * 8]);
    load_lds16(&WT[(size_t)(col0 + sr + 64 ) * 1024 + k0 + sk], &Bs[(size_t)(tid + 256) * 8]);
    __syncthreads();
    short8 a[4], b[4];
    #pragma unroll
    for (int i = 0; i < 4; i++) a[i] = *(const short8*)&As[(wm + i*16 + ln) * 32 + quad * 8];
    #pragma unroll
    for (int j = 0; j < 4; j++) b[j] = *(const short8*)&Bs[(wn + j*16 + ln) * 32 + quad * 8];
    #pragma unroll
    for (int i = 0; i < 4; i++)
      #pragma unroll
      for (int j = 0; j < 4; j++)
        acc[i][j] = __builtin_amdgcn_mfma_f32_16x16x32_bf16(a[i], b[j], acc[i][j], 0, 0, 0);
  }

  // epilogue: C-layout col = lane&15, row = quad*4 + reg
  const int wcol0 = col0 + wn;            // 64-aligned -> single (which, head) per wave
  const int which = wcol0 >> 10;          // 0=q 1=k 2=v  (block-uniform: col0 is 128-aligned)
  const int h = (wcol0 & 1023) >> 6;
  float bs[4];
  #pragma unroll
  for (int j = 0; j < 4; j++) bs[j] = bias[wcol0 + j*16 + ln];

  if (which < 2){
    #pragma unroll
    for (int i = 0; i < 4; i++){
      #pragma unroll
      for (int rr = 0; rr < 4; rr++){
        const int rowg = row0 + wm + i*16 + quad*4 + rr;
        const int b_ = rowg >> 11, t = rowg & 2047;
        u16* op = (which == 0 ? Qb : Kb) + ((size_t)(b_ * NHEAD + h) * TT + t) * HD;
        #pragma unroll
        for (int j = 0; j < 2; j++){
          const int f = j*16 + ln;
          const float cs = ropeC[t * 32 + f];
          const float sn = ropeS[t * 32 + f];
          const float x1 = acc[i][j  ][rr] + bs[j  ];
          const float x2 = acc[i][j+2][rr] + bs[j+2];
          float y1 = x1 * cs - x2 * sn;
          float y2 = x1 * sn + x2 * cs;
          if (which == 0){ y1 *= 0.125f; y2 *= 0.125f; }
          op[f]      = f2bf(y1);
          op[f + 32] = f2bf(y2);
        }
      }
    }
  } else {
    // V: per-wave LDS transpose in 16-t chunks -> coalesced 16B stores along t.
    #pragma unroll
    for (int i = 0; i < 4; i++){
      #pragma unroll
      for (int j = 0; j < 4; j++)
        #pragma unroll
        for (int rr = 0; rr < 4; rr++)
          VTx[wid][(j*16 + ln) * 24 + quad*4 + rr] = f2bf(acc[i][j][rr] + bs[j]);
      asm volatile("s_waitcnt lgkmcnt(0)" ::: "memory");   // cross-lane in-wave LDS RAW
      const int d = lane;                                   // 0..63
      const short8 v0 = *(const short8*)&VTx[wid][d * 24 + 0];
      const short8 v1 = *(const short8*)&VTx[wid][d * 24 + 8];
      const int rowg = row0 + wm + i*16;
      const int b_ = rowg >> 11, t0 = rowg & 2047;
      u16* vp = &Vtg[((size_t)(b_ * NHEAD + h) * HD + d) * TT + t0];
      *(short8*)&vp[0] = v0;
      *(short8*)&vp[8] = v1;
      asm volatile("s_waitcnt lgkmcnt(0)" ::: "memory");   // reads done before next chunk's writes
    }
  }
}

// ---------------- flash attention v10 (round-8 measured best: 78.7 us) ----------------
__global__ void __launch_bounds__(256, 3)
attn(const u16* __restrict__ Qb, const u16* __restrict__ Kb,
     const u16* __restrict__ Vtg, u16* __restrict__ AO)
{
  const int bh = blockIdx.x, tbi = 15 - (int)blockIdx.y;
  const int tid = threadIdx.x;
  const int wid = tid >> 6, lane = tid & 63;
  const int quad = lane >> 4, ln = lane & 15;

  __shared__ alignas(16) u16 Kl2[2][64 * 72];       // [buf][key][d], pad 72
  __shared__ alignas(16) u16 Vt2[2][64 * 72];       // [buf][d][key], pad 72
  __shared__ alignas(16) float Plf[4][16 * 68];     // per-wave f32 P tile, stride 68 (bank-balanced)

  const u16* Qh = Qb  + (size_t)bh * TT * HD;
  const u16* Kh = Kb  + (size_t)bh * TT * HD;
  const u16* Vh = Vtg + (size_t)bh * HD * TT;       // [d][t]
  const int b_ = bh >> 4, h = bh & 15;

  const int qbase = tbi * 128 + wid * 32;           // wave owns rows [qbase, qbase+31]

  short8 aq[2][2];
  #pragma unroll
  for (int qt = 0; qt < 2; qt++){
    aq[qt][0] = *(const short8*)&Qh[(size_t)(qbase + qt*16 + ln) * HD + quad*8];
    aq[qt][1] = *(const short8*)&Qh[(size_t)(qbase + qt*16 + ln) * HD + 32 + quad*8];
  }

  floatx4 o[2][4] = {};
  float l_i[2][4] = {};
  float* Pf = &Plf[wid][0];

  // staging geometry: thread covers rows pr and pr+32, 8 threads x 16B per row
  const int pr = tid >> 3, pc = (tid & 7) * 8;
  short8 kpre0, kpre1, vpre0, vpre1;

  const int nch = 2 * (tbi + 1);

  // prologue: chunk 0 -> regs -> buf0
  kpre0 = *(const short8*)&Kh[(size_t)(pr     ) * HD + pc];
  kpre1 = *(const short8*)&Kh[(size_t)(pr + 32) * HD + pc];
  vpre0 = *(const short8*)&Vh[(size_t)(pr     ) * TT + pc];
  vpre1 = *(const short8*)&Vh[(size_t)(pr + 32) * TT + pc];
  *(short8*)&Kl2[0][(pr     ) * 72 + pc] = kpre0;
  *(short8*)&Kl2[0][(pr + 32) * 72 + pc] = kpre1;
  *(short8*)&Vt2[0][(pr     ) * 72 + pc] = vpre0;
  *(short8*)&Vt2[0][(pr + 32) * 72 + pc] = vpre1;
  __syncthreads();

  int cur = 0;
  for (int ch = 0; ch < nch; ++ch){
    const int key0 = ch * 64;
    // load-early: next chunk's global loads go in flight over this chunk's compute
    if (ch + 1 < nch){
      const int nk0 = key0 + 64;
      kpre0 = *(const short8*)&Kh[(size_t)(nk0 + pr     ) * HD + pc];
      kpre1 = *(const short8*)&Kh[(size_t)(nk0 + pr + 32) * HD + pc];
      vpre0 = *(const short8*)&Vh[(size_t)(pr     ) * TT + nk0 + pc];
      vpre1 = *(const short8*)&Vh[(size_t)(pr + 32) * TT + nk0 + pc];
    }

    // wave-uniform skip: chunk entirely above this wave's diagonal
    if (key0 <= qbase + 31){
      const u16* Kl = Kl2[cur];
      const u16* Vt = Vt2[cur];
      const bool act0 = (key0 <= qbase + 15);     // qt=0 tile not fully masked
      short8 pk0[2], pk1[2];                      // PV A-frags (key halves) per qt
      #pragma unroll
      for (int qt = 0; qt < 2; qt++){
        if (qt == 0 && !act0) continue;
        const int qt0 = qbase + qt*16;
        // S = Q K^T for this q-tile
        floatx4 z[4];
        #pragma unroll
        for (int j = 0; j < 4; j++){
          const short8 kb0 = *(const short8*)&Kl[(j*16 + ln) * 72 + quad*8];
          const short8 kb1 = *(const short8*)&Kl[(j*16 + ln) * 72 + 32 + quad*8];
          floatx4 zz = {0.0f, 0.0f, 0.0f, 0.0f};
          zz = __builtin_amdgcn_mfma_f32_16x16x32_bf16(aq[qt][0], kb0, zz, 0, 0, 0);
          zz = __builtin_amdgcn_mfma_f32_16x16x32_bf16(aq[qt][1], kb1, zz, 0, 0, 0);
          z[j] = zz;
        }
        if (key0 + 63 > qt0){                     // near-diagonal: apply causal mask
          #pragma unroll
          for (int j = 0; j < 4; j++)
            #pragma unroll
            for (int rr = 0; rr < 4; rr++){
              const int key = key0 + j*16 + ln;
              const int t   = qt0 + quad*4 + rr;
              if (key > t) z[j][rr] = NEGINF;
            }
        }
        // p = exp(s), fixed m=0; store RAW f32 to LDS (stride 68: bank-balanced)
        #pragma unroll
        for (int j = 0; j < 4; j++)
          #pragma unroll
          for (int rr = 0; rr < 4; rr++){
            const float p = __expf(z[j][rr]);
            l_i[qt][rr] += p;
            Pf[(quad*4 + rr) * 68 + j*16 + ln] = p;
          }
        asm volatile("s_waitcnt lgkmcnt(0)" ::: "memory");  // cross-lane in-wave LDS RAW
        pk0[qt] = cvt8(&Pf[ln * 68 + quad*8]);              // keys 0..31 A-frag
        pk1[qt] = cvt8(&Pf[ln * 68 + 32 + quad*8]);         // keys 32..63 A-frag
      }
      // PV: vb read once, both q-tiles
      #pragma unroll
      for (int n = 0; n < 4; n++){
        const short8 vb0 = *(const short8*)&Vt[(n*16 + ln) * 72 + quad*8];
        const short8 vb1 = *(const short8*)&Vt[(n*16 + ln) * 72 + 32 + quad*8];
        if (act0){
          o[0][n] = __builtin_amdgcn_mfma_f32_16x16x32_bf16(pk0[0], vb0, o[0][n], 0, 0, 0);
          o[0][n] = __builtin_amdgcn_mfma_f32_16x16x32_bf16(pk1[0], vb1, o[0][n], 0, 0, 0);
        }
        o[1][n] = __builtin_amdgcn_mfma_f32_16x16x32_bf16(pk0[1], vb0, o[1][n], 0, 0, 0);
        o[1][n] = __builtin_amdgcn_mfma_f32_16x16x32_bf16(pk1[1], vb1, o[1][n], 0, 0, 0);
      }
    }

    // write-late: commit prefetched chunk to the OTHER buffer (vmcnt waits here,
    // after compute). Safe: buf[cur^1] was last read in iter ch-1, sealed by its barrier.
    if (ch + 1 < nch){
      *(short8*)&Kl2[cur ^ 1][(pr     ) * 72 + pc] = kpre0;
      *(short8*)&Kl2[cur ^ 1][(pr + 32) * 72 + pc] = kpre1;
      *(short8*)&Vt2[cur ^ 1][(pr     ) * 72 + pc] = vpre0;
      *(short8*)&Vt2[cur ^ 1][(pr + 32) * 72 + pc] = vpre1;
    }
    __syncthreads();                              // ONE barrier per chunk
    cur ^= 1;
  }

  // reduce l over the quad's 16 lanes (once, after the loop)
  #pragma unroll
  for (int qt = 0; qt < 2; qt++)
    #pragma unroll
    for (int rr = 0; rr < 4; rr++){
      float rs = l_i[qt][rr];
      #pragma unroll
      for (int off = 1; off < 16; off <<= 1) rs += __shfl_xor(rs, off);
      l_i[qt][rr] = rs;
    }

  // epilogue: AO[b][t][h*64+d]
  #pragma unroll
  for (int qt = 0; qt < 2; qt++)
    #pragma unroll
    for (int n = 0; n < 4; n++)
      #pragma unroll
      for (int rr = 0; rr < 4; rr++){
        const int t = qbase + qt*16 + quad*4 + rr;
        const float inv_l = 1.0f / fmaxf(l_i[qt][rr], 1e-20f);
        AO[(size_t)(b_ * TT + t) * HIDDEN + h * HD + n*16 + ln] = f2bf(o[qt][n][rr] * inv_l);
      }
}

// ---------------- GEMM2: out = AO @ Wproj + bproj -> fp32 out (round-0) ----------------
__global__ void gemm_proj(const u16* __restrict__ A, const u16* __restrict__ WT,
                          const float* __restrict__ bias, float* __restrict__ out)
{
  __shared__ alignas(16) u16 As[128 * 32];
  __shared__ alignas(16) u16 Bs[128 * 32];
  const int tid = threadIdx.x;
  const int wid = tid >> 6, lane = tid & 63;
  const int quad = lane >> 4, ln = lane & 15;
  const int row0 = blockIdx.y * 128, col0 = blockIdx.x * 128;
  const int wm = (wid >> 1) * 64, wn = (wid & 1) * 64;
  floatx4 acc[4][4] = {};

  const int sr = tid >> 2, sk = (tid & 3) * 8;

  for (int kk = 0; kk < 32; ++kk){
    const int k0 = kk * 32;
    __syncthreads();
    load_lds16(&A [(size_t)(row0 + sr      ) * 1024 + k0 + sk], &As[(size_t)(tid      ) * 8]);
    load_lds16(&A [(size_t)(row0 + sr + 64 ) * 1024 + k0 + sk], &As[(size_t)(tid + 256) * 8]);
    load_lds16(&WT[(size_t)(col0 + sr      ) * 1024 + k0 + sk], &Bs[(size_t)(tid      ) * 8]);
    load_lds16(&WT[(size_t)(col0 + sr + 64 ) * 1024 + k0 + sk], &Bs[(size_t)(tid + 256) * 8]);
    __syncthreads();
    short8 a[4], b[4];
    #pragma unroll
    for (int i = 0; i < 4; i++) a[i] = *(const short8*)&As[(wm + i*16 + ln) * 32 + quad * 8];
    #pragma unroll
    for (int j = 0; j < 4; j++) b[j] = *(const short8*)&Bs[(wn + j*16 + ln) * 32 + quad * 8];
    #pragma unroll
    for (int i = 0; i < 4; i++)
      #pragma unroll
      for (int j = 0; j < 4; j++)
        acc[i][j] = __builtin_amdgcn_mfma_f32_16x16x32_bf16(a[i], b[j], acc[i][j], 0, 0, 0);
  }

  float bs[4];
  #pragma unroll
  for (int j = 0; j < 4; j++) bs[j] = bias[col0 + wn + j*16 + ln];
  #pragma unroll
  for (int i = 0; i < 4; i++)
    #pragma unroll
    for (int rr = 0; rr < 4; rr++){
      const int rowg = row0 + wm + i*16 + quad*4 + rr;
      #pragma unroll
      for (int j = 0; j < 4; j++)
        out[(size_t)rowg * HIDDEN + col0 + wn + j*16 + ln] = acc[i][j][rr] + bs[j];
    }
}

extern "C" void kernel_launch(void* const* d_in, const int* in_sizes, int n_in,
                              void* d_out, int out_size, void* d_ws, size_t ws_size,
                              hipStream_t stream)
{
  const float* x     = (const float*)d_in[0];
  const float* rnn   = (const float*)d_in[1];
  const float* Wqkv  = (const float*)d_in[2];
  const float* bqkv  = (const float*)d_in[3];
  const float* Wproj = (const float*)d_in[4];
  const float* bproj = (const float*)d_in[5];
  float* out = (float*)d_out;

  // ---- workspace layout (byte offsets, 16B-aligned), ~93 MB ----
  char* ws = (char*)d_ws;
  size_t off = 0;
  float* ropeC  = (float*)(ws + off); off += (size_t)TT * 32 * 4;
  float* ropeS  = (float*)(ws + off); off += (size_t)TT * 32 * 4;
  u16*   xN     = (u16*)(ws + off);   off += (size_t)MM * HIDDEN * 2;
  u16*   WqkvT  = (u16*)(ws + off);   off += (size_t)NQKV * HIDDEN * 2;
  u16*   WprojT = (u16*)(ws + off);   off += (size_t)HIDDEN * HIDDEN * 2;
  u16*   Qb     = (u16*)(ws + off);   off += (size_t)MM * HIDDEN * 2;
  u16*   Kb     = (u16*)(ws + off);   off += (size_t)MM * HIDDEN * 2;
  u16*   Vtg    = (u16*)(ws + off);   off += (size_t)MM * HIDDEN * 2;   // V^T [bh][d][t]
  u16*   AO     = (u16*)(ws + off);   off += (size_t)MM * HIDDEN * 2;

  prep<<<PREP_BLKS, 256, 0, stream>>>(x, xN, Wqkv, WqkvT, Wproj, WprojT,
                                      ropeC, ropeS, rnn, out);
  gemm_qkv<<<dim3(NQKV / 128, MM / 128), 256, 0, stream>>>(xN, WqkvT, bqkv, ropeC, ropeS, Qb, Kb, Vtg);
  attn<<<dim3(BB * NHEAD, 16), 256, 0, stream>>>(Qb, Kb, Vtg, AO);
  gemm_proj<<<dim3(HIDDEN / 128, MM / 128), 256, 0, stream>>>(AO, WprojT, bproj, out);
}